// Round 2
// baseline (427.946 us; speedup 1.0000x reference)
//
#include <hip/hip_runtime.h>

// SSIM loss: separable 11x11 Gaussian (window = outer(g,g), g recovered as
// row-sums of the provided 2D window), 5 quantities, SSIM map, global mean.
//
// R2: vertical-pass-first + TY=16 tile -> LDS 41.5KB -> ~22.8KB,
// occupancy 3 -> 7 blocks/CU. v_rcp_f32 for the SSIM divide (thr 2e-2).

#define TX 32
#define TY 16
#define HALO 5
#define WSZ 11
#define LX (TX + 2 * HALO)      // 42
#define LY (TY + 2 * HALO)      // 26
#define LXP (LX + 1)            // 43 — stagger banks across rows

__global__ void ssim_init(float* acc) {
    if (threadIdx.x == 0) acc[0] = 0.0f;
}

__global__ __launch_bounds__(256) void ssim_main(
    const float* __restrict__ x, const float* __restrict__ y,
    const float* __restrict__ w2d, float* __restrict__ acc,
    int H, int W)
{
    __shared__ float sx[LY][LXP];
    __shared__ float sy[LY][LXP];
    __shared__ float vx[TY][LXP];
    __shared__ float vy[TY][LXP];
    __shared__ float vxx[TY][LXP];
    __shared__ float vyy[TY][LXP];
    __shared__ float vxy[TY][LXP];
    __shared__ float g[WSZ];
    __shared__ float wred[4];

    const int tid = threadIdx.x;

    // Recover normalized 1D kernel from 2D window (row sums; channels identical).
    if (tid < WSZ) {
        float s = 0.0f;
        #pragma unroll
        for (int j = 0; j < WSZ; ++j) s += w2d[tid * WSZ + j];
        g[tid] = s;
    }

    const int z = blockIdx.z;
    const float* __restrict__ xp = x + (size_t)z * H * W;
    const float* __restrict__ yp = y + (size_t)z * H * W;
    const int x0 = blockIdx.x * TX - HALO;
    const int y0 = blockIdx.y * TY - HALO;

    // Phase A: stage input tile + halo (zero-padded at image borders).
    for (int idx = tid; idx < LY * LX; idx += 256) {
        const int r = idx / LX, c = idx - r * LX;
        const int gr = y0 + r, gc = x0 + c;
        float xv = 0.0f, yv = 0.0f;
        if (gr >= 0 && gr < H && gc >= 0 && gc < W) {
            const int o = gr * W + gc;
            xv = xp[o];
            yv = yp[o];
        }
        sx[r][c] = xv;
        sy[r][c] = yv;
    }
    __syncthreads();

    // Phase B: VERTICAL pass over all LX columns -> [TY][LX] x 5 quantities.
    for (int idx = tid; idx < TY * LX; idx += 256) {
        const int r = idx / LX, c = idx - r * LX;
        float ax = 0.f, ay = 0.f, axx = 0.f, ayy = 0.f, axy = 0.f;
        #pragma unroll
        for (int k = 0; k < WSZ; ++k) {
            const float gv = g[k];
            const float xv = sx[r + k][c];
            const float yv = sy[r + k][c];
            ax  = fmaf(gv, xv, ax);
            ay  = fmaf(gv, yv, ay);
            axx = fmaf(gv, xv * xv, axx);
            ayy = fmaf(gv, yv * yv, ayy);
            axy = fmaf(gv, xv * yv, axy);
        }
        vx[r][c] = ax;   vy[r][c] = ay;
        vxx[r][c] = axx; vyy[r][c] = ayy; vxy[r][c] = axy;
    }
    __syncthreads();

    // Phase C: horizontal pass + SSIM. 512 outputs = exactly 2 per thread.
    float lsum = 0.0f;
    #pragma unroll
    for (int it = 0; it < (TY * TX) / 256; ++it) {
        const int idx = tid + it * 256;
        const int r = idx >> 5, c = idx & 31;
        float mx = 0.f, my = 0.f, sxx = 0.f, syy = 0.f, sxy = 0.f;
        #pragma unroll
        for (int k = 0; k < WSZ; ++k) {
            const float gv = g[k];
            mx  = fmaf(gv, vx[r][c + k], mx);
            my  = fmaf(gv, vy[r][c + k], my);
            sxx = fmaf(gv, vxx[r][c + k], sxx);
            syy = fmaf(gv, vyy[r][c + k], syy);
            sxy = fmaf(gv, vxy[r][c + k], sxy);
        }
        const float mx2 = mx * mx, my2 = my * my, mxy = mx * my;
        const float vvx = sxx - mx2, vvy = syy - my2, vvxy = sxy - mxy;
        const float C1 = 1e-4f, C2 = 9e-4f;
        const float num = (2.0f * mxy + C1) * (2.0f * vvxy + C2);
        const float den = (mx2 + my2 + C1) * (vvx + vvy + C2) + 1e-12f;
        // den >= C1*C2 > 0; v_rcp_f32 rel err ~1e-5 << 2e-2 threshold.
        lsum = fmaf(num, __builtin_amdgcn_rcpf(den), lsum);
    }

    // Wave reduce (64 lanes) -> cross-wave via LDS -> one atomic per block.
    #pragma unroll
    for (int off = 32; off > 0; off >>= 1)
        lsum += __shfl_down(lsum, off, 64);
    const int lane = tid & 63, wave = tid >> 6;
    if (lane == 0) wred[wave] = lsum;
    __syncthreads();
    if (tid == 0) {
        atomicAdd(acc, wred[0] + wred[1] + wred[2] + wred[3]);
    }
}

__global__ void ssim_final(const float* __restrict__ acc,
                           float* __restrict__ out, float invN) {
    if (threadIdx.x == 0) out[0] = 1.0f - acc[0] * invN;
}

extern "C" void kernel_launch(void* const* d_in, const int* in_sizes, int n_in,
                              void* d_out, int out_size, void* d_ws, size_t ws_size,
                              hipStream_t stream) {
    const float* x   = (const float*)d_in[0];
    const float* y   = (const float*)d_in[1];
    const float* w2d = (const float*)d_in[2];  // (3,1,11,11); channels identical
    float* out = (float*)d_out;
    float* acc = (float*)d_ws;

    const int H = 512, W = 512;
    const int total = in_sizes[0];          // 16*3*512*512
    const int Z = total / (H * W);          // 48 images*channels

    ssim_init<<<1, 64, 0, stream>>>(acc);

    dim3 grid(W / TX, H / TY, Z);           // 16 x 32 x 48 = 24576 blocks
    ssim_main<<<grid, 256, 0, stream>>>(x, y, w2d, acc, H, W);

    const float invN = 1.0f / (float)total;
    ssim_final<<<1, 64, 0, stream>>>(acc, out, invN);
}

// Round 3
// 343.001 us; speedup vs baseline: 1.2477x; 1.2477x over previous
//
#include <hip/hip_runtime.h>

// SSIM loss, separable 11x11 Gaussian. R3: the bottleneck is the LDS pipe
// (R1 == 182us == exact b32-LDS-throughput roofline; R2's vertical pass added
// 12x bank conflicts). Fix: ds_read_b128 everywhere + register reuse.
//  - Horizontal pass: 4 outputs/thread from 8 aligned float4 LDS reads.
//  - Vertical pass: 4 cols x 2 rows/thread; each h row read once (float4),
//    feeds both rows' register accumulators.
//  - Tile 64x32, LDS ~79KB, 2 blocks/CU. Patterns conflict-free per
//    8-lane phase group (row strides 76 and 64 words, quads aligned).
//  - Finalize folded into main via ticket counter (last block writes out).

#define HALO 5
#define WSZ 11
#define TX 64
#define TY 32
#define LXI (TX + 2*HALO)     // 74
#define LYI (TY + 2*HALO)     // 42
#define SW  76                // input tile stride (words, mult of 4)
#define NQ  (TX/4)            // 16 quads per row
#define NBQ (LYI * NQ)        // 672 horizontal quad-items

__global__ void ssim_init(float* ws) {
    if (threadIdx.x == 0) { ws[0] = 0.0f; ((unsigned*)ws)[1] = 0u; }
}

__global__ __launch_bounds__(256) void ssim_main(
    const float* __restrict__ xg, const float* __restrict__ yg,
    const float* __restrict__ w2d, float* __restrict__ ws,
    float* __restrict__ out, int nblocks, float invN)
{
    __shared__ float sx[LYI * SW];
    __shared__ float sy[LYI * SW];
    __shared__ float h[5][LYI * TX];
    __shared__ float gs[WSZ];
    __shared__ float wred[4];

    const int tid = threadIdx.x;

    // 1D kernel = row sums of the 2D window (window = outer(g,g), sum 1).
    if (tid < WSZ) {
        float s = 0.0f;
        #pragma unroll
        for (int j = 0; j < WSZ; ++j) s += w2d[tid * WSZ + j];
        gs[tid] = s;
    }

    const int H = 512, W = 512;
    const float* __restrict__ xp = xg + (size_t)blockIdx.z * H * W;
    const float* __restrict__ yp = yg + (size_t)blockIdx.z * H * W;
    const int x0 = blockIdx.x * TX - HALO;
    const int y0 = blockIdx.y * TY - HALO;

    // Phase A: stage input tile + halo (zero-padded at image borders).
    for (int idx = tid; idx < LYI * LXI; idx += 256) {
        const int r = idx / LXI, c = idx - r * LXI;
        const int gr = y0 + r, gc = x0 + c;
        float xv = 0.0f, yv = 0.0f;
        if ((unsigned)gr < 512u && (unsigned)gc < 512u) {
            const int o = gr * W + gc;
            xv = xp[o]; yv = yp[o];
        }
        sx[r * SW + c] = xv;
        sy[r * SW + c] = yv;
    }
    __syncthreads();

    float g[WSZ];
    #pragma unroll
    for (int k = 0; k < WSZ; ++k) g[k] = gs[k];

    // Phase B: horizontal pass. One quad (4 consecutive outputs) per item.
    // Reads 16 floats per input via 4 aligned b128; taps use [0..13].
    for (int q = tid; q < NBQ; q += 256) {
        const int r = q >> 4, cq = q & 15;
        const int base = r * SW + 4 * cq;
        float xa[16], ya[16];
        *(float4*)&xa[0]  = *(const float4*)&sx[base];
        *(float4*)&xa[4]  = *(const float4*)&sx[base + 4];
        *(float4*)&xa[8]  = *(const float4*)&sx[base + 8];
        *(float4*)&xa[12] = *(const float4*)&sx[base + 12];
        *(float4*)&ya[0]  = *(const float4*)&sy[base];
        *(float4*)&ya[4]  = *(const float4*)&sy[base + 4];
        *(float4*)&ya[8]  = *(const float4*)&sy[base + 8];
        *(float4*)&ya[12] = *(const float4*)&sy[base + 12];

        float xx[14], yy[14], xy[14];
        #pragma unroll
        for (int i = 0; i < 14; ++i) {
            xx[i] = xa[i] * xa[i];
            yy[i] = ya[i] * ya[i];
            xy[i] = xa[i] * ya[i];
        }

        float ax[4], ay[4], axx[4], ayy[4], axy[4];
        #pragma unroll
        for (int j = 0; j < 4; ++j) {
            ax[j] = ay[j] = axx[j] = ayy[j] = axy[j] = 0.0f;
        }
        #pragma unroll
        for (int k = 0; k < WSZ; ++k) {
            const float gv = g[k];
            #pragma unroll
            for (int j = 0; j < 4; ++j) {
                ax[j]  = fmaf(gv, xa[j + k], ax[j]);
                ay[j]  = fmaf(gv, ya[j + k], ay[j]);
                axx[j] = fmaf(gv, xx[j + k], axx[j]);
                ayy[j] = fmaf(gv, yy[j + k], ayy[j]);
                axy[j] = fmaf(gv, xy[j + k], axy[j]);
            }
        }

        const int ob = r * TX + 4 * cq;
        *(float4*)&h[0][ob] = make_float4(ax[0],  ax[1],  ax[2],  ax[3]);
        *(float4*)&h[1][ob] = make_float4(ay[0],  ay[1],  ay[2],  ay[3]);
        *(float4*)&h[2][ob] = make_float4(axx[0], axx[1], axx[2], axx[3]);
        *(float4*)&h[3][ob] = make_float4(ayy[0], ayy[1], ayy[2], ayy[3]);
        *(float4*)&h[4][ob] = make_float4(axy[0], axy[1], axy[2], axy[3]);
    }
    __syncthreads();

    // Phase C: vertical pass. Thread = 4 cols x 2 rows; 12 h-rows x 5
    // quantities read once each (b128), feeding both rows' accumulators.
    float a0[5][4], a1[5][4];
    #pragma unroll
    for (int t = 0; t < 5; ++t)
        #pragma unroll
        for (int j = 0; j < 4; ++j) { a0[t][j] = 0.0f; a1[t][j] = 0.0f; }

    const int cq = tid & 15, rq = tid >> 4;
    const int c0 = 4 * cq, r0 = 2 * rq;     // r0 in {0..30}
    #pragma unroll
    for (int j = 0; j < 12; ++j) {
        #pragma unroll
        for (int t = 0; t < 5; ++t) {
            const float4 v = *(const float4*)&h[t][(r0 + j) * TX + c0];
            if (j < 11) {
                const float gv = g[j];
                a0[t][0] = fmaf(gv, v.x, a0[t][0]);
                a0[t][1] = fmaf(gv, v.y, a0[t][1]);
                a0[t][2] = fmaf(gv, v.z, a0[t][2]);
                a0[t][3] = fmaf(gv, v.w, a0[t][3]);
            }
            if (j >= 1) {
                const float gv = g[j - 1];
                a1[t][0] = fmaf(gv, v.x, a1[t][0]);
                a1[t][1] = fmaf(gv, v.y, a1[t][1]);
                a1[t][2] = fmaf(gv, v.z, a1[t][2]);
                a1[t][3] = fmaf(gv, v.w, a1[t][3]);
            }
        }
    }

    float lsum = 0.0f;
    const float C1 = 1e-4f, C2 = 9e-4f;
    auto ssim4 = [&](float (&a)[5][4]) {
        #pragma unroll
        for (int j = 0; j < 4; ++j) {
            const float mx = a[0][j], my = a[1][j];
            const float pxx = a[2][j], pyy = a[3][j], pxy = a[4][j];
            const float mx2 = mx * mx, my2 = my * my, mxy = mx * my;
            const float vx = pxx - mx2, vy = pyy - my2, vxy = pxy - mxy;
            const float num = (2.0f * mxy + C1) * (2.0f * vxy + C2);
            const float den = (mx2 + my2 + C1) * (vx + vy + C2) + 1e-12f;
            // den >= C1*C2 > 0; v_rcp_f32 rel err ~1e-5 << 2e-2 threshold.
            lsum = fmaf(num, __builtin_amdgcn_rcpf(den), lsum);
        }
    };
    ssim4(a0);
    ssim4(a1);

    // Wave reduce -> cross-wave -> one atomic; last block finalizes.
    #pragma unroll
    for (int off = 32; off > 0; off >>= 1)
        lsum += __shfl_down(lsum, off, 64);
    if ((tid & 63) == 0) wred[tid >> 6] = lsum;
    __syncthreads();
    if (tid == 0) {
        atomicAdd(&ws[0], wred[0] + wred[1] + wred[2] + wred[3]);
        __threadfence();
        const unsigned old = atomicAdd((unsigned*)ws + 1, 1u);
        if (old == (unsigned)(nblocks - 1)) {
            __threadfence();
            const float total = atomicAdd(&ws[0], 0.0f);  // coherent read
            out[0] = 1.0f - total * invN;
        }
    }
}

extern "C" void kernel_launch(void* const* d_in, const int* in_sizes, int n_in,
                              void* d_out, int out_size, void* d_ws, size_t ws_size,
                              hipStream_t stream) {
    const float* x   = (const float*)d_in[0];
    const float* y   = (const float*)d_in[1];
    const float* w2d = (const float*)d_in[2];  // (3,1,11,11); channels identical
    float* out = (float*)d_out;
    float* ws  = (float*)d_ws;

    const int H = 512, W = 512;
    const int total = in_sizes[0];              // 16*3*512*512
    const int Z = total / (H * W);              // 48

    ssim_init<<<1, 64, 0, stream>>>(ws);

    dim3 grid(W / TX, H / TY, Z);               // 8 x 16 x 48 = 6144 blocks
    const int nblocks = (W / TX) * (H / TY) * Z;
    const float invN = 1.0f / (float)total;
    ssim_main<<<grid, 256, 0, stream>>>(x, y, w2d, ws, out, nblocks, invN);
}